// Round 9
// baseline (146.774 us; speedup 1.0000x reference)
//
#include <hip/hip_runtime.h>
#include <hip/hip_bf16.h>

// ConvolutionalAttention2D: B=16, C=256, N=H*W=4096.
// out = (Wo * (phiQ @ phiV^T)) @ phiK + bo, phiX = elu(Wx @ x)+1
// bf16 MFMA (16x16x32), fp32 accumulate.
// Round 9: kill the xT materialization — k_proj reads x (f32) directly and
// does transpose+cvt in registers during B-staging. Engines = r4 known-good.

typedef short  bf16x8 __attribute__((ext_vector_type(8)));
typedef float  f32x4  __attribute__((ext_vector_type(4)));
typedef unsigned short u16x4 __attribute__((ext_vector_type(4)));

#define NB 16
#define NC 256
#define NN 4096

__device__ __forceinline__ unsigned short f2bf(float f) {
    union { float f; unsigned u; } v; v.f = f;
    unsigned r = v.u + 0x7FFFu + ((v.u >> 16) & 1u);
    return (unsigned short)(r >> 16);
}

__device__ __forceinline__ float phi_act(float v) {
    return v > 0.f ? v + 1.f : __expf(v);
}

__device__ __forceinline__ void gload_lds16(const void* g, void* l) {
    __builtin_amdgcn_global_load_lds(
        (const __attribute__((address_space(1))) void*)g,
        (__attribute__((address_space(3))) void*)l, 16, 0, 0);
}

// Stage a 128row x 64k bf16 tile (16 KB) into linear LDS with XOR-swizzled
// SOURCE address (both-sides swizzle; reads use frag_ld's matching XOR).
__device__ __forceinline__ void stage_tile(
    const unsigned short* __restrict__ src, int ld, int kb, char* lds, int t)
{
    const int kslot  = t & 7;
    const int rbase  = t >> 3;                         // 0..31
    const int srcOff = (kslot * 16) ^ ((rbase & 7) << 4);
    const int wbase  = (t >> 6) * 1024;                // wave-uniform
    #pragma unroll
    for (int i = 0; i < 4; ++i) {
        const int r = i * 32 + rbase;
        const char* g = (const char*)(src + (size_t)r * ld + kb) + srcOff;
        gload_lds16(g, lds + i * 4096 + wbase);
    }
}

// Swizzled fragment read: row-major [128][64] bf16, byte ^= ((row&7)<<4)
__device__ __forceinline__ bf16x8 frag_ld(const char* lds, int row, int kbyte) {
    return *(const bf16x8*)(lds + row * 128 + (kbyte ^ ((row & 7) << 4)));
}

// ---------------------------------------------------------------------------
// k_proj engine: A (weights, bf16) via gload_lds; B = x tile (f32, [c][n])
// transposed+converted in registers, written swizzled to [n][k] LDS.
// 2-barrier drain per 64-k step (proven safe). 128x128 out tile, 4 waves.
// ---------------------------------------------------------------------------
template<bool SWAP>
__device__ __forceinline__ void gemm_projx(
    const unsigned short* __restrict__ A,      // [128][256] weight slab
    const float* __restrict__ xb,              // x[b] + n0  ([c][n], ld=NN)
    char* lsA, char* lsB, f32x4 (&acc)[4][4])
{
    const int t = threadIdx.x, lane = t & 63, w = t >> 6;
    const int wr = (w >> 1) * 64, wc = (w & 1) * 64;
    const int q = lane >> 4, c15 = lane & 15;
    const int cb = t & 15;            // k-block (4 c-rows)
    const int nb0 = t >> 4;           // n-block base (4 n-cols), +16 for unit 1

    for (int kt = 0; kt < 4; ++kt) {
        const int kb = kt * 64;
        // issue B loads to regs BEFORE barrier (overlap with prior compute)
        f32x4 bv[2][4];
        #pragma unroll
        for (int i = 0; i < 2; ++i) {
            const float* src = xb + (size_t)(kb + cb * 4) * NN + (nb0 + 16 * i) * 4;
            #pragma unroll
            for (int j = 0; j < 4; ++j)
                bv[i][j] = *(const f32x4*)(src + (size_t)j * NN);
        }
        if (kt) __syncthreads();          // prior reads done before overwrite
        stage_tile(A, NC, kb, lsA, t);    // A: 4 gload_lds
        // B: cvt + micro-transpose, swizzled ds_write_b64
        #pragma unroll
        for (int i = 0; i < 2; ++i) {
            const int nb = nb0 + 16 * i;
            #pragma unroll
            for (int jj = 0; jj < 4; ++jj) {
                const int n = nb * 4 + jj;
                u16x4 wv;
                #pragma unroll
                for (int j = 0; j < 4; ++j) wv[j] = f2bf(bv[i][j][jj]);
                *(u16x4*)(lsB + n * 128 + ((cb * 8) ^ ((n & 7) << 4))) = wv;
            }
        }
        __syncthreads();                  // drains vmcnt + lgkmcnt
        #pragma unroll
        for (int g = 0; g < 2; ++g) {
            const int kbyte = g * 64 + q * 16;
            bf16x8 af[4], bfr[4];
            #pragma unroll
            for (int m = 0; m < 4; ++m) af[m]  = frag_ld(lsA, wr + m * 16 + c15, kbyte);
            #pragma unroll
            for (int n = 0; n < 4; ++n) bfr[n] = frag_ld(lsB, wc + n * 16 + c15, kbyte);
            #pragma unroll
            for (int m = 0; m < 4; ++m)
                #pragma unroll
                for (int n = 0; n < 4; ++n)
                    acc[m][n] = SWAP
                        ? __builtin_amdgcn_mfma_f32_16x16x32_bf16(bfr[n], af[m], acc[m][n], 0, 0, 0)
                        : __builtin_amdgcn_mfma_f32_16x16x32_bf16(af[m], bfr[n], acc[m][n], 0, 0, 0);
        }
    }
}

// ---------------------------------------------------------------------------
// Round-2 2-barrier 128x128 engine (k_qv, k_mproj, k_out) — known good.
// ---------------------------------------------------------------------------
template<bool SWAP>
__device__ __forceinline__ void gemm128(
    const unsigned short* __restrict__ A, int lda,
    const unsigned short* __restrict__ BT, int ldb,
    int k0, int nk, char* lsA, char* lsB, f32x4 (&acc)[4][4])
{
    const int t = threadIdx.x;
    const int lane = t & 63;
    const int w  = t >> 6;
    const int wr = (w >> 1) * 64, wc = (w & 1) * 64;
    const int q  = lane >> 4, c15 = lane & 15;

    for (int kt = 0; kt < nk; ++kt) {
        const int kb = k0 + kt * 64;
        if (kt) __syncthreads();
        stage_tile(A,  lda, kb, lsA, t);
        stage_tile(BT, ldb, kb, lsB, t);
        __syncthreads();
        #pragma unroll
        for (int g = 0; g < 2; ++g) {
            const int kbyte = g * 64 + q * 16;
            bf16x8 af[4], bfr[4];
            #pragma unroll
            for (int m = 0; m < 4; ++m) af[m]  = frag_ld(lsA, wr + m * 16 + c15, kbyte);
            #pragma unroll
            for (int n = 0; n < 4; ++n) bfr[n] = frag_ld(lsB, wc + n * 16 + c15, kbyte);
            #pragma unroll
            for (int m = 0; m < 4; ++m)
                #pragma unroll
                for (int n = 0; n < 4; ++n)
                    acc[m][n] = SWAP
                        ? __builtin_amdgcn_mfma_f32_16x16x32_bf16(bfr[n], af[m], acc[m][n], 0, 0, 0)
                        : __builtin_amdgcn_mfma_f32_16x16x32_bf16(af[m], bfr[n], acc[m][n], 0, 0, 0);
        }
    }
}

// ---- K0: weights -> bf16 (x is no longer preprocessed) ---------------------
__global__ __launch_bounds__(256) void k_wcvt(
    const float* __restrict__ Wq, const float* __restrict__ Wk,
    const float* __restrict__ Wv, const float* __restrict__ Wo,
    unsigned short* __restrict__ Wqkv, unsigned short* __restrict__ Wob)
{
    int i = blockIdx.x * 256 + threadIdx.x;        // 262144 total
    if      (i < 65536)  Wqkv[i] = f2bf(Wq[i]);
    else if (i < 131072) Wqkv[i] = f2bf(Wk[i - 65536]);
    else if (i < 196608) Wqkv[i] = f2bf(Wv[i - 131072]);
    else if (i < 262144) Wob[i - 196608] = f2bf(Wo[i - 196608]);
}

// ------ K1: [phiQ;phiK^T;phiV] = phi(Wqkv @ x); grid 16b*6mt*32nt -----------
__global__ __launch_bounds__(256) void k_proj(
    const unsigned short* __restrict__ Wqkv, const float* __restrict__ x,
    unsigned short* __restrict__ phiQ, unsigned short* __restrict__ phiKT,
    unsigned short* __restrict__ phiV)
{
    __shared__ __align__(16) char lds[32768];
    const int bid = blockIdx.x;                    // 3072
    const int nt  = bid & 31;
    const int mt  = (bid >> 5) % 6;
    const int b   = bid / 192;
    const unsigned short* A = Wqkv + (size_t)mt * 128 * NC;
    const float* xb = x + (size_t)b * NC * NN + nt * 128;

    const int lane = threadIdx.x & 63;
    const int w    = threadIdx.x >> 6;
    const int wr   = (w >> 1) * 64, wc = (w & 1) * 64;
    const int q4   = (lane >> 4) * 4, c15 = lane & 15;
    const int p    = mt >> 1;                 // 0=Q, 1=K, 2=V

    f32x4 acc[4][4] = {};
    if (p == 1) {
        gemm_projx<false>(A, xb, lds, lds + 16384, acc);
        // phiKT[n][c]: regs span c -> packed u16x4 along c
        unsigned short* dst = phiKT + (size_t)b * NN * NC;
        const int cb = (mt & 1) * 128 + wr + q4;
        const int nb = nt * 128 + wc + c15;
        #pragma unroll
        for (int m = 0; m < 4; ++m)
            #pragma unroll
            for (int n = 0; n < 4; ++n) {
                u16x4 pk;
                #pragma unroll
                for (int i = 0; i < 4; ++i) pk[i] = f2bf(phi_act(acc[m][n][i]));
                *(u16x4*)(dst + (size_t)(nb + n * 16) * NC + cb + m * 16) = pk;
            }
    } else {
        gemm_projx<true>(A, xb, lds, lds + 16384, acc);
        // phi{Q,V}[c][n]: SWAP -> regs span n -> packed u16x4 along n
        unsigned short* dst = (p == 0 ? phiQ : phiV) + (size_t)b * NC * NN;
        const int ob = (mt & 1) * 128 + wr + c15;
        const int nb = nt * 128 + wc + q4;
        #pragma unroll
        for (int m = 0; m < 4; ++m)
            #pragma unroll
            for (int n = 0; n < 4; ++n) {
                u16x4 pk;
                #pragma unroll
                for (int i = 0; i < 4; ++i) pk[i] = f2bf(phi_act(acc[m][n][i]));
                *(u16x4*)(dst + (size_t)(ob + m * 16) * NN + nb + n * 16) = pk;
            }
    }
}

// ------ K2: qvT_part[s][b][d][c] partials, split-K=8 ------------------------
__global__ __launch_bounds__(256) void k_qv(
    const unsigned short* __restrict__ phiQ, const unsigned short* __restrict__ phiV,
    float* __restrict__ qvTp)
{
    __shared__ char lds[32768];
    const int bid = blockIdx.x;                    // 512 blocks
    const int s = bid & 7, nt = (bid >> 3) & 1, mt = (bid >> 4) & 1, b = bid >> 5;
    const unsigned short* A  = phiQ + ((size_t)b * NC + mt * 128) * NN;
    const unsigned short* BT = phiV + ((size_t)b * NC + nt * 128) * NN;
    f32x4 acc[4][4] = {};
    gemm128<false>(A, NN, BT, NN, s * 512, 8, lds, lds + 16384, acc);

    const int lane = threadIdx.x & 63, w = threadIdx.x >> 6;
    const int wr = (w >> 1) * 64, wc = (w & 1) * 64;
    const int q4 = (lane >> 4) * 4, c15 = lane & 15;
    float* dst = qvTp + (((size_t)s * NB + b) << 16);
    const int c0 = mt * 128 + wr + q4;
    const int d0 = nt * 128 + wc + c15;
    #pragma unroll
    for (int m = 0; m < 4; ++m)
        #pragma unroll
        for (int n = 0; n < 4; ++n)
            *(f32x4*)(dst + (size_t)(d0 + n * 16) * NC + c0 + m * 16) = acc[m][n];
}

// ------ K2b: qvT[b][d][c] bf16 = sum_s partials -----------------------------
__global__ __launch_bounds__(256) void k_qvred(
    const float* __restrict__ p, unsigned short* __restrict__ qvT)
{
    const size_t i = (size_t)blockIdx.x * 256 + threadIdx.x;  // 262144 f32x4 units
    const f32x4* pv = (const f32x4*)p;
    f32x4 v = pv[i];
    #pragma unroll
    for (int s = 1; s < 8; ++s) v = v + pv[i + (size_t)s * 262144];
    u16x4 o;
    #pragma unroll
    for (int j = 0; j < 4; ++j) o[j] = f2bf(v[j]);
    ((u16x4*)qvT)[i] = o;
}

// ------ K3: Mb[b][o][d] = Wo @ qv  (SWAP: regs span d) -----------------------
__global__ __launch_bounds__(256) void k_mproj(
    const unsigned short* __restrict__ Wob, const unsigned short* __restrict__ qvT,
    unsigned short* __restrict__ Mb)
{
    __shared__ char lds[32768];
    const int bid = blockIdx.x;                    // 64 blocks
    const int nt = bid & 1, mt = (bid >> 1) & 1, b = bid >> 2;
    const unsigned short* A  = Wob + mt * 128 * NC;
    const unsigned short* BT = qvT + ((size_t)b << 16) + nt * 128 * NC;
    f32x4 acc[4][4] = {};
    gemm128<true>(A, NC, BT, NC, 0, 4, lds, lds + 16384, acc);

    const int lane = threadIdx.x & 63, w = threadIdx.x >> 6;
    const int wr = (w >> 1) * 64, wc = (w & 1) * 64;
    const int q4 = (lane >> 4) * 4, c15 = lane & 15;
    unsigned short* dst = Mb + ((size_t)b << 16);
    const int ob = mt * 128 + wr + c15;
    const int db = nt * 128 + wc + q4;
    #pragma unroll
    for (int m = 0; m < 4; ++m)
        #pragma unroll
        for (int n = 0; n < 4; ++n) {
            u16x4 pk;
            #pragma unroll
            for (int i = 0; i < 4; ++i) pk[i] = f2bf(acc[m][n][i]);
            *(u16x4*)(dst + (size_t)(ob + m * 16) * NC + db + n * 16) = pk;
        }
}

// ------ K4: out[b][o][n] = Mb @ phiK + bo  (SWAP: regs span n, f32x4 stores) -
__global__ __launch_bounds__(256) void k_out(
    const unsigned short* __restrict__ Mb, const unsigned short* __restrict__ phiKT,
    const float* __restrict__ bo, float* __restrict__ out)
{
    __shared__ char lds[32768];
    const int bid = blockIdx.x;                    // 1024 blocks
    const int nt = bid & 31, mt = (bid >> 5) & 1, b = bid >> 6;
    const unsigned short* A  = Mb + ((size_t)b << 16) + mt * 128 * NC;
    const unsigned short* BT = phiKT + (size_t)b * NN * NC + (size_t)nt * 128 * NC;
    f32x4 acc[4][4] = {};
    gemm128<true>(A, NC, BT, NC, 0, 4, lds, lds + 16384, acc);

    const int lane = threadIdx.x & 63, w = threadIdx.x >> 6;
    const int wr = (w >> 1) * 64, wc = (w & 1) * 64;
    const int q4 = (lane >> 4) * 4, c15 = lane & 15;
    float* dst = out + (size_t)b * NC * NN;
    #pragma unroll
    for (int m = 0; m < 4; ++m) {
        const int o  = mt * 128 + wr + m * 16 + c15;
        const float bb = bo[o];
        #pragma unroll
        for (int n = 0; n < 4; ++n) {
            f32x4 v = acc[m][n];
            #pragma unroll
            for (int i = 0; i < 4; ++i) v[i] += bb;
            *(f32x4*)(dst + (size_t)o * NN + nt * 128 + wc + n * 16 + q4) = v;
        }
    }
}

// ---------------------------------------------------------------------------
extern "C" void kernel_launch(void* const* d_in, const int* in_sizes, int n_in,
                              void* d_out, int out_size, void* d_ws, size_t ws_size,
                              hipStream_t stream)
{
    (void)in_sizes; (void)n_in; (void)out_size; (void)ws_size;
    const float* x  = (const float*)d_in[0];
    const float* Wq = (const float*)d_in[1];
    const float* Wk = (const float*)d_in[2];
    const float* Wv = (const float*)d_in[3];
    const float* Wo = (const float*)d_in[4];
    const float* bo = (const float*)d_in[5];
    float* out = (float*)d_out;

    char* ws = (char*)d_ws;
    size_t off = 0;
    auto alloc = [&](size_t bytes) {
        void* p = ws + off;
        off += (bytes + 255) & ~(size_t)255;
        return p;
    };
    unsigned short* phiQ  = (unsigned short*)alloc((size_t)NB * NC * NN * 2); // 32 MiB
    unsigned short* phiV  = (unsigned short*)alloc((size_t)NB * NC * NN * 2); // 32 MiB
    unsigned short* phiKT = (unsigned short*)alloc((size_t)NB * NN * NC * 2); // 32 MiB
    float*          qvTp  = (float*)alloc((size_t)8 * NB * NC * NC * 4);      // 32 MiB
    unsigned short* qvT   = (unsigned short*)alloc((size_t)NB * NC * NC * 2); //  2 MiB
    unsigned short* Mb    = (unsigned short*)alloc((size_t)NB * NC * NC * 2); //  2 MiB
    unsigned short* Wqkv  = (unsigned short*)alloc((size_t)768 * NC * 2);
    unsigned short* Wob   = (unsigned short*)alloc((size_t)NC * NC * 2);

    k_wcvt<<<1024, 256, 0, stream>>>(Wq, Wk, Wv, Wo, Wqkv, Wob);
    k_proj<<<3072, 256, 0, stream>>>(Wqkv, x, phiQ, phiKT, phiV);
    k_qv<<<512, 256, 0, stream>>>(phiQ, phiV, qvTp);
    k_qvred<<<1024, 256, 0, stream>>>(qvTp, qvT);
    k_mproj<<<64, 256, 0, stream>>>(Wob, qvT, Mb);
    k_out<<<1024, 256, 0, stream>>>(Mb, phiKT, bo, out);
}

// Round 10
// 125.605 us; speedup vs baseline: 1.1685x; 1.1685x over previous
//
#include <hip/hip_runtime.h>
#include <hip/hip_bf16.h>

// ConvolutionalAttention2D: B=16, C=256, N=H*W=4096.
// out = (Wo * (phiQ @ phiV^T)) @ phiK + bo, phiX = elu(Wx @ x)+1
// bf16 MFMA (16x16x32), fp32 accumulate.
// Round 10: consolidate on proven r2 engines (2-barrier drain). Fused k_pre.
// NEW: k_out merges both Mb slabs per block (A=256 rows) — halves phiKT
// re-reads, doubles MFMA per stage stall. No XCD swizzle, no counted vmcnt.

typedef short  bf16x8 __attribute__((ext_vector_type(8)));
typedef float  f32x4  __attribute__((ext_vector_type(4)));
typedef unsigned short u16x4 __attribute__((ext_vector_type(4)));

#define NB 16
#define NC 256
#define NN 4096

__device__ __forceinline__ unsigned short f2bf(float f) {
    union { float f; unsigned u; } v; v.f = f;
    unsigned r = v.u + 0x7FFFu + ((v.u >> 16) & 1u);
    return (unsigned short)(r >> 16);
}

__device__ __forceinline__ float phi_act(float v) {
    return v > 0.f ? v + 1.f : __expf(v);
}

__device__ __forceinline__ void gload_lds16(const void* g, void* l) {
    __builtin_amdgcn_global_load_lds(
        (const __attribute__((address_space(1))) void*)g,
        (__attribute__((address_space(3))) void*)l, 16, 0, 0);
}

// Stage an NR-row x 64k bf16 tile (NR*128 B) into linear LDS with XOR-swizzled
// SOURCE address (both-sides swizzle; reads use frag_ld's matching XOR).
template<int NR>
__device__ __forceinline__ void stage_tile(
    const unsigned short* __restrict__ src, int ld, int kb, char* lds, int t)
{
    const int kslot  = t & 7;
    const int rbase  = t >> 3;                         // 0..31
    const int srcOff = (kslot * 16) ^ ((rbase & 7) << 4);
    const int wbase  = (t >> 6) * 1024;                // wave-uniform
    #pragma unroll
    for (int i = 0; i < NR / 32; ++i) {
        const int r = i * 32 + rbase;
        const char* g = (const char*)(src + (size_t)r * ld + kb) + srcOff;
        gload_lds16(g, lds + i * 4096 + wbase);
    }
}

// Swizzled fragment read: row-major [NR][64] bf16, byte ^= ((row&7)<<4)
__device__ __forceinline__ bf16x8 frag_ld(const char* lds, int row, int kbyte) {
    return *(const bf16x8*)(lds + row * 128 + (kbyte ^ ((row & 7) << 4)));
}

// ---------------------------------------------------------------------------
// r2 2-barrier 128x128 engine (proj/qv/mproj) — known good.
// SWAP=false: acc[m][n] rows = A-dim (wr+m*16+q4+i), cols = B-dim (wc+n*16+c15)
// SWAP=true : acc[m][n] rows = B-dim (wc+n*16+q4+i), cols = A-dim (wr+m*16+c15)
// ---------------------------------------------------------------------------
template<bool SWAP>
__device__ __forceinline__ void gemm128(
    const unsigned short* __restrict__ A, int lda,
    const unsigned short* __restrict__ BT, int ldb,
    int k0, int nk, char* lsA, char* lsB, f32x4 (&acc)[4][4])
{
    const int t = threadIdx.x;
    const int lane = t & 63;
    const int w  = t >> 6;
    const int wr = (w >> 1) * 64, wc = (w & 1) * 64;
    const int q  = lane >> 4, c15 = lane & 15;

    for (int kt = 0; kt < nk; ++kt) {
        const int kb = k0 + kt * 64;
        if (kt) __syncthreads();            // prior reads done before overwrite
        stage_tile<128>(A,  lda, kb, lsA, t);
        stage_tile<128>(BT, ldb, kb, lsB, t);
        __syncthreads();                    // compiler drains vmcnt before barrier
        #pragma unroll
        for (int g = 0; g < 2; ++g) {
            const int kbyte = g * 64 + q * 16;
            bf16x8 af[4], bfr[4];
            #pragma unroll
            for (int m = 0; m < 4; ++m) af[m]  = frag_ld(lsA, wr + m * 16 + c15, kbyte);
            #pragma unroll
            for (int n = 0; n < 4; ++n) bfr[n] = frag_ld(lsB, wc + n * 16 + c15, kbyte);
            #pragma unroll
            for (int m = 0; m < 4; ++m)
                #pragma unroll
                for (int n = 0; n < 4; ++n)
                    acc[m][n] = SWAP
                        ? __builtin_amdgcn_mfma_f32_16x16x32_bf16(bfr[n], af[m], acc[m][n], 0, 0, 0)
                        : __builtin_amdgcn_mfma_f32_16x16x32_bf16(af[m], bfr[n], acc[m][n], 0, 0, 0);
        }
    }
}

// ---- K0 (fused): xpose (blocks 0..4095) + weight convert (blocks 4096..5119)
__global__ __launch_bounds__(256) void k_pre(
    const float* __restrict__ x,
    const float* __restrict__ Wq, const float* __restrict__ Wk,
    const float* __restrict__ Wv, const float* __restrict__ Wo,
    unsigned short* __restrict__ xT,
    unsigned short* __restrict__ Wqkv, unsigned short* __restrict__ Wob)
{
    __shared__ float tile[64][68];
    const int id = blockIdx.x;
    if (id >= 4096) {
        int i = (id - 4096) * 256 + threadIdx.x;   // 262144 total
        if      (i < 65536)  Wqkv[i] = f2bf(Wq[i]);
        else if (i < 131072) Wqkv[i] = f2bf(Wk[i - 65536]);
        else if (i < 196608) Wqkv[i] = f2bf(Wv[i - 131072]);
        else                 Wob[i - 196608] = f2bf(Wo[i - 196608]);
        return;
    }
    const int b  = id >> 8;
    const int n0 = (id & 63) * 64, c0 = ((id >> 6) & 3) * 64;
    const int t  = threadIdx.x;
    const float* xp = x + ((size_t)b * NC + c0) * NN + n0;
    const int cc = t >> 4, nq = t & 15;
    #pragma unroll
    for (int j = 0; j < 4; ++j) {
        const int c = j * 16 + cc;
        f32x4 v = *(const f32x4*)(xp + (size_t)c * NN + nq * 4);
        *(f32x4*)&tile[c][nq * 4] = v;
    }
    __syncthreads();
    unsigned short* op = xT + ((size_t)b * NN + n0) * NC + c0;
    const int nn0 = t >> 4, cq = t & 15;
    #pragma unroll
    for (int j = 0; j < 4; ++j) {
        const int nn = j * 16 + nn0;
        u16x4 o;
        #pragma unroll
        for (int ii = 0; ii < 4; ++ii) o[ii] = f2bf(tile[cq * 4 + ii][nn]);
        *(u16x4*)(op + (size_t)nn * NC + cq * 4) = o;
    }
}

// ------ K1: [phiQ;phiK^T;phiV] = phi(Wqkv @ x); grid 16b*6mt*32nt (r2) ------
__global__ __launch_bounds__(256) void k_proj(
    const unsigned short* __restrict__ Wqkv, const unsigned short* __restrict__ xT,
    unsigned short* __restrict__ phiQ, unsigned short* __restrict__ phiKT,
    unsigned short* __restrict__ phiV)
{
    __shared__ char lds[32768];
    const int bid = blockIdx.x;                    // 3072
    const int nt  = bid & 31;
    const int mt  = (bid >> 5) % 6;
    const int b   = bid / 192;
    const unsigned short* A  = Wqkv + (size_t)mt * 128 * NC;
    const unsigned short* BT = xT + ((size_t)b * NN + nt * 128) * NC;

    const int lane = threadIdx.x & 63;
    const int w    = threadIdx.x >> 6;
    const int wr   = (w >> 1) * 64, wc = (w & 1) * 64;
    const int q4   = (lane >> 4) * 4, c15 = lane & 15;
    const int p    = mt >> 1;                 // 0=Q, 1=K, 2=V

    f32x4 acc[4][4] = {};
    if (p == 1) {
        gemm128<false>(A, NC, BT, NC, 0, 4, lds, lds + 16384, acc);
        // phiKT[n][c]: regs span c -> packed u16x4 along c
        unsigned short* dst = phiKT + (size_t)b * NN * NC;
        const int cb = (mt & 1) * 128 + wr + q4;
        const int nb = nt * 128 + wc + c15;
        #pragma unroll
        for (int m = 0; m < 4; ++m)
            #pragma unroll
            for (int n = 0; n < 4; ++n) {
                u16x4 pk;
                #pragma unroll
                for (int i = 0; i < 4; ++i) pk[i] = f2bf(phi_act(acc[m][n][i]));
                *(u16x4*)(dst + (size_t)(nb + n * 16) * NC + cb + m * 16) = pk;
            }
    } else {
        gemm128<true>(A, NC, BT, NC, 0, 4, lds, lds + 16384, acc);
        // phi{Q,V}[c][n]: SWAP -> regs span n -> packed u16x4 along n
        unsigned short* dst = (p == 0 ? phiQ : phiV) + (size_t)b * NC * NN;
        const int ob = (mt & 1) * 128 + wr + c15;
        const int nb = nt * 128 + wc + q4;
        #pragma unroll
        for (int m = 0; m < 4; ++m)
            #pragma unroll
            for (int n = 0; n < 4; ++n) {
                u16x4 pk;
                #pragma unroll
                for (int i = 0; i < 4; ++i) pk[i] = f2bf(phi_act(acc[m][n][i]));
                *(u16x4*)(dst + (size_t)(ob + m * 16) * NN + nb + n * 16) = pk;
            }
    }
}

// ------ K2: qvT_part[s][b][d][c] partials, split-K=8 (r2) -------------------
__global__ __launch_bounds__(256) void k_qv(
    const unsigned short* __restrict__ phiQ, const unsigned short* __restrict__ phiV,
    float* __restrict__ qvTp)
{
    __shared__ char lds[32768];
    const int bid = blockIdx.x;                    // 512 blocks
    const int s = bid & 7, nt = (bid >> 3) & 1, mt = (bid >> 4) & 1, b = bid >> 5;
    const unsigned short* A  = phiQ + ((size_t)b * NC + mt * 128) * NN;
    const unsigned short* BT = phiV + ((size_t)b * NC + nt * 128) * NN;
    f32x4 acc[4][4] = {};
    gemm128<false>(A, NN, BT, NN, s * 512, 8, lds, lds + 16384, acc);

    const int lane = threadIdx.x & 63, w = threadIdx.x >> 6;
    const int wr = (w >> 1) * 64, wc = (w & 1) * 64;
    const int q4 = (lane >> 4) * 4, c15 = lane & 15;
    float* dst = qvTp + (((size_t)s * NB + b) << 16);
    const int c0 = mt * 128 + wr + q4;
    const int d0 = nt * 128 + wc + c15;
    #pragma unroll
    for (int m = 0; m < 4; ++m)
        #pragma unroll
        for (int n = 0; n < 4; ++n)
            *(f32x4*)(dst + (size_t)(d0 + n * 16) * NC + c0 + m * 16) = acc[m][n];
}

// ------ K2b: qvT[b][d][c] bf16 = sum_s partials -----------------------------
__global__ __launch_bounds__(256) void k_qvred(
    const float* __restrict__ p, unsigned short* __restrict__ qvT)
{
    const size_t i = (size_t)blockIdx.x * 256 + threadIdx.x;  // 262144 f32x4 units
    const f32x4* pv = (const f32x4*)p;
    f32x4 v = pv[i];
    #pragma unroll
    for (int s = 1; s < 8; ++s) v = v + pv[i + (size_t)s * 262144];
    u16x4 o;
    #pragma unroll
    for (int j = 0; j < 4; ++j) o[j] = f2bf(v[j]);
    ((u16x4*)qvT)[i] = o;
}

// ------ K3: Mb[b][o][d] = Wo @ qv  (SWAP: regs span d; r2) ------------------
__global__ __launch_bounds__(256) void k_mproj(
    const unsigned short* __restrict__ Wob, const unsigned short* __restrict__ qvT,
    unsigned short* __restrict__ Mb)
{
    __shared__ char lds[32768];
    const int bid = blockIdx.x;                    // 64 blocks
    const int nt = bid & 1, mt = (bid >> 1) & 1, b = bid >> 2;
    const unsigned short* A  = Wob + mt * 128 * NC;
    const unsigned short* BT = qvT + ((size_t)b << 16) + nt * 128 * NC;
    f32x4 acc[4][4] = {};
    gemm128<true>(A, NC, BT, NC, 0, 4, lds, lds + 16384, acc);

    const int lane = threadIdx.x & 63, w = threadIdx.x >> 6;
    const int wr = (w >> 1) * 64, wc = (w & 1) * 64;
    const int q4 = (lane >> 4) * 4, c15 = lane & 15;
    unsigned short* dst = Mb + ((size_t)b << 16);
    const int ob = mt * 128 + wr + c15;
    const int db = nt * 128 + wc + q4;
    #pragma unroll
    for (int m = 0; m < 4; ++m)
        #pragma unroll
        for (int n = 0; n < 4; ++n) {
            u16x4 pk;
            #pragma unroll
            for (int i = 0; i < 4; ++i) pk[i] = f2bf(acc[m][n][i]);
            *(u16x4*)(dst + (size_t)(ob + m * 16) * NC + db + n * 16) = pk;
        }
}

// ------ K4: out[b][:][n-tile] = Mb[b](256x256) @ phiK-tile + bo -------------
// Merged-mt: A = FULL Mb slab (stage_tile<256>, 32 KB), B = 128-row phiKT tile.
// 4 waves each own 64 o-rows x 128 n. SWAP: acc[m][n] rows=n-dim, cols=o-dim.
// 64 MFMA/wave/step — 2x math per stage stall vs r2; halves phiKT re-reads.
__global__ __launch_bounds__(256) void k_out(
    const unsigned short* __restrict__ Mb, const unsigned short* __restrict__ phiKT,
    const float* __restrict__ bo, float* __restrict__ out)
{
    __shared__ __align__(16) char lds[49152];
    char* lsA = lds;            // [256][64k] = 32 KB
    char* lsB = lds + 32768;    // [128][64k] = 16 KB
    const int bid = blockIdx.x;                    // 512
    const int ng = bid & 31, b = bid >> 5;
    const unsigned short* A  = Mb + ((size_t)b << 16);                  // [256][256]
    const unsigned short* BT = phiKT + ((size_t)b * NN + ng * 128) * NC; // [128][256]
    float* dst = out + (size_t)b * NC * NN;

    const int t = threadIdx.x, lane = t & 63, w = t >> 6;
    const int wr = w * 64;                         // o-range per wave
    const int q = lane >> 4, c15 = lane & 15;

    f32x4 acc[4][8] = {};
    for (int kt = 0; kt < 4; ++kt) {
        if (kt) __syncthreads();
        stage_tile<256>(A,  NC, kt * 64, lsA, t);
        stage_tile<128>(BT, NC, kt * 64, lsB, t);
        __syncthreads();
        #pragma unroll
        for (int g = 0; g < 2; ++g) {
            const int kbyte = g * 64 + q * 16;
            bf16x8 afr[4], bfr[8];
            #pragma unroll
            for (int m = 0; m < 4; ++m) afr[m] = frag_ld(lsA, wr + m * 16 + c15, kbyte);
            #pragma unroll
            for (int n = 0; n < 8; ++n) bfr[n] = frag_ld(lsB, n * 16 + c15, kbyte);
            #pragma unroll
            for (int m = 0; m < 4; ++m)
                #pragma unroll
                for (int n = 0; n < 8; ++n)   // SWAP: rows=n-dim, cols=o-dim
                    acc[m][n] = __builtin_amdgcn_mfma_f32_16x16x32_bf16(
                        bfr[n], afr[m], acc[m][n], 0, 0, 0);
        }
    }
    const int q4 = q * 4;
    #pragma unroll
    for (int m = 0; m < 4; ++m) {
        const int o = wr + m * 16 + c15;
        const float bb = bo[o];
        #pragma unroll
        for (int n = 0; n < 8; ++n) {
            f32x4 v = acc[m][n];
            #pragma unroll
            for (int i = 0; i < 4; ++i) v[i] += bb;
            *(f32x4*)(dst + (size_t)o * NN + ng * 128 + n * 16 + q4) = v;
        }
    }
}

// ---------------------------------------------------------------------------
extern "C" void kernel_launch(void* const* d_in, const int* in_sizes, int n_in,
                              void* d_out, int out_size, void* d_ws, size_t ws_size,
                              hipStream_t stream)
{
    (void)in_sizes; (void)n_in; (void)out_size; (void)ws_size;
    const float* x  = (const float*)d_in[0];
    const float* Wq = (const float*)d_in[1];
    const float* Wk = (const float*)d_in[2];
    const float* Wv = (const float*)d_in[3];
    const float* Wo = (const float*)d_in[4];
    const float* bo = (const float*)d_in[5];
    float* out = (float*)d_out;

    char* ws = (char*)d_ws;
    size_t off = 0;
    auto alloc = [&](size_t bytes) {
        void* p = ws + off;
        off += (bytes + 255) & ~(size_t)255;
        return p;
    };
    unsigned short* xT    = (unsigned short*)alloc((size_t)NB * NN * NC * 2); // 32 MiB
    unsigned short* phiQ  = (unsigned short*)alloc((size_t)NB * NC * NN * 2); // 32 MiB
    unsigned short* phiV  = (unsigned short*)alloc((size_t)NB * NC * NN * 2); // 32 MiB
    unsigned short* phiKT = (unsigned short*)alloc((size_t)NB * NN * NC * 2); // 32 MiB
    unsigned short* qvT   = (unsigned short*)alloc((size_t)NB * NC * NC * 2); //  2 MiB
    unsigned short* Mb    = (unsigned short*)alloc((size_t)NB * NC * NC * 2); //  2 MiB
    unsigned short* Wqkv  = (unsigned short*)alloc((size_t)768 * NC * 2);
    unsigned short* Wob   = (unsigned short*)alloc((size_t)NC * NC * 2);
    float* qvTp = (float*)xT;   // alias: xT dead after k_proj; 8*16*64K*4B = 32 MiB

    k_pre<<<5120, 256, 0, stream>>>(x, Wq, Wk, Wv, Wo, xT, Wqkv, Wob);
    k_proj<<<3072, 256, 0, stream>>>(Wqkv, xT, phiQ, phiKT, phiV);
    k_qv<<<512, 256, 0, stream>>>(phiQ, phiV, qvTp);
    k_qvred<<<1024, 256, 0, stream>>>(qvTp, qvT);
    k_mproj<<<64, 256, 0, stream>>>(Wob, qvT, Mb);
    k_out<<<512, 256, 0, stream>>>(Mb, phiKT, bo, out);
}

// Round 11
// 122.876 us; speedup vs baseline: 1.1945x; 1.0222x over previous
//
#include <hip/hip_runtime.h>
#include <hip/hip_bf16.h>

// ConvolutionalAttention2D: B=16, C=256, N=H*W=4096.
// out = (Wo * (phiQ @ phiV^T)) @ phiK + bo, phiX = elu(Wx @ x)+1
// bf16 MFMA (16x16x32), fp32 accumulate.
// Round 11: k_projm transposes x in-LDS once per block (B-resident across
// Q/K/V slabs) — kills the xT HBM round-trip. k_qv gets XCD swizzle (r4-best),
// k_out reverts to r2 form (r10's merged k_out regressed ~5us).

typedef short  bf16x8 __attribute__((ext_vector_type(8)));
typedef float  f32x4  __attribute__((ext_vector_type(4)));
typedef unsigned short u16x4 __attribute__((ext_vector_type(4)));

#define NB 16
#define NC 256
#define NN 4096

__device__ __forceinline__ unsigned short f2bf(float f) {
    union { float f; unsigned u; } v; v.f = f;
    unsigned r = v.u + 0x7FFFu + ((v.u >> 16) & 1u);
    return (unsigned short)(r >> 16);
}

__device__ __forceinline__ float phi_act(float v) {
    return v > 0.f ? v + 1.f : __expf(v);
}

__device__ __forceinline__ void gload_lds16(const void* g, void* l) {
    __builtin_amdgcn_global_load_lds(
        (const __attribute__((address_space(1))) void*)g,
        (__attribute__((address_space(3))) void*)l, 16, 0, 0);
}

// Stage a 128row x 64k bf16 tile (16 KB) into linear LDS with XOR-swizzled
// SOURCE address (both-sides swizzle; reads use frag_ld's matching XOR).
template<int NR>
__device__ __forceinline__ void stage_tile(
    const unsigned short* __restrict__ src, int ld, int kb, char* lds, int t)
{
    const int kslot  = t & 7;
    const int rbase  = t >> 3;                         // 0..31
    const int srcOff = (kslot * 16) ^ ((rbase & 7) << 4);
    const int wbase  = (t >> 6) * 1024;                // wave-uniform
    #pragma unroll
    for (int i = 0; i < NR / 32; ++i) {
        const int r = i * 32 + rbase;
        const char* g = (const char*)(src + (size_t)r * ld + kb) + srcOff;
        gload_lds16(g, lds + i * 4096 + wbase);
    }
}

// A-side swizzled fragment read: row-major [128][64] bf16, byte ^= ((row&7)<<4)
__device__ __forceinline__ bf16x8 frag_ld(const char* lds, int row, int kbyte) {
    return *(const bf16x8*)(lds + row * 128 + (kbyte ^ ((row & 7) << 4)));
}

// B-side (resident xTl [128 n][256 k] bf16, row=512B) with 2-level XOR:
// f(n) = ((n&7)<<4) ^ ((n&24)<<1). Read: 16 consecutive n -> 2-way (free).
__device__ __forceinline__ bf16x8 fragB_ld(const char* lds, int n, int kbyte) {
    const int fo = ((n & 7) << 4) ^ ((n & 24) << 1);
    return *(const bf16x8*)(lds + n * 512 + (kbyte ^ fo));
}

// ---------------------------------------------------------------------------
// r2 2-barrier 128x128 engine (qv/mproj/out) — known good.
// SWAP=false: acc[m][n] rows = A-dim (wr+m*16+q4+i), cols = B-dim (wc+n*16+c15)
// SWAP=true : acc[m][n] rows = B-dim (wc+n*16+q4+i), cols = A-dim (wr+m*16+c15)
// ---------------------------------------------------------------------------
template<bool SWAP>
__device__ __forceinline__ void gemm128(
    const unsigned short* __restrict__ A, int lda,
    const unsigned short* __restrict__ BT, int ldb,
    int k0, int nk, char* lsA, char* lsB, f32x4 (&acc)[4][4])
{
    const int t = threadIdx.x;
    const int lane = t & 63;
    const int w  = t >> 6;
    const int wr = (w >> 1) * 64, wc = (w & 1) * 64;
    const int q  = lane >> 4, c15 = lane & 15;

    for (int kt = 0; kt < nk; ++kt) {
        const int kb = k0 + kt * 64;
        if (kt) __syncthreads();            // prior reads done before overwrite
        stage_tile<128>(A,  lda, kb, lsA, t);
        stage_tile<128>(BT, ldb, kb, lsB, t);
        __syncthreads();                    // compiler drains vmcnt before barrier
        #pragma unroll
        for (int g = 0; g < 2; ++g) {
            const int kbyte = g * 64 + q * 16;
            bf16x8 af[4], bfr[4];
            #pragma unroll
            for (int m = 0; m < 4; ++m) af[m]  = frag_ld(lsA, wr + m * 16 + c15, kbyte);
            #pragma unroll
            for (int n = 0; n < 4; ++n) bfr[n] = frag_ld(lsB, wc + n * 16 + c15, kbyte);
            #pragma unroll
            for (int m = 0; m < 4; ++m)
                #pragma unroll
                for (int n = 0; n < 4; ++n)
                    acc[m][n] = SWAP
                        ? __builtin_amdgcn_mfma_f32_16x16x32_bf16(bfr[n], af[m], acc[m][n], 0, 0, 0)
                        : __builtin_amdgcn_mfma_f32_16x16x32_bf16(af[m], bfr[n], acc[m][n], 0, 0, 0);
        }
    }
}

// ---- K0: weights -> bf16 ----------------------------------------------------
__global__ __launch_bounds__(256) void k_wcvt(
    const float* __restrict__ Wq, const float* __restrict__ Wk,
    const float* __restrict__ Wv, const float* __restrict__ Wo,
    unsigned short* __restrict__ Wqkv, unsigned short* __restrict__ Wob)
{
    int i = blockIdx.x * 256 + threadIdx.x;        // 262144 total
    if      (i < 65536)  Wqkv[i] = f2bf(Wq[i]);
    else if (i < 131072) Wqkv[i] = f2bf(Wk[i - 65536]);
    else if (i < 196608) Wqkv[i] = f2bf(Wv[i - 131072]);
    else if (i < 262144) Wob[i - 196608] = f2bf(Wo[i - 196608]);
}

// ---- K1: phi projections, merged 3-slab, in-LDS x transpose ----------------
// grid 1024 = 16b x 2half x 32nt. LDS: xTl [128 n][256 k] bf16 (64 KB,
// resident) + lsA 16 KB streaming = 80 KB -> 2 blocks/CU.
__global__ __launch_bounds__(256) void k_projm(
    const unsigned short* __restrict__ Wqkv, const float* __restrict__ x,
    unsigned short* __restrict__ phiQ, unsigned short* __restrict__ phiKT,
    unsigned short* __restrict__ phiV)
{
    __shared__ __align__(16) char lds[81920];
    char* xTl = lds;                 // 65536 B
    char* lsA = lds + 65536;         // 16384 B
    const int bid = blockIdx.x;
    const int nt = bid & 31, ph = (bid >> 5) & 1, b = bid >> 6;
    const float* xb = x + (size_t)b * NC * NN + nt * 128;
    const int t = threadIdx.x;

    // ---- transpose x-tile [256 c][128 n] f32 -> xTl [128 n][256 c] bf16
    {
        const int n4 = (t & 31) * 4;           // n quad base (coalesced reads)
        const int c0 = t >> 5;                 // 0..7
        #pragma unroll 4
        for (int cc = 0; cc < 32; ++cc) {
            const int c = cc * 8 + c0;
            f32x4 v = *(const f32x4*)(xb + (size_t)c * NN + n4);
            #pragma unroll
            for (int i = 0; i < 4; ++i) {
                const int n = n4 + i;
                const int fo = ((n & 7) << 4) ^ ((n & 24) << 1);
                *(unsigned short*)(xTl + n * 512 + ((2 * c) ^ fo)) = f2bf(v[i]);
            }
        }
    }

    const int lane = t & 63, w = t >> 6;
    const int wr = (w >> 1) * 64, wc = (w & 1) * 64;
    const int q = lane >> 4, c15 = lane & 15;
    const int q4 = q * 4;

    #pragma unroll
    for (int slab = 0; slab < 3; ++slab) {     // 0=Q, 1=K, 2=V
        const int mt = slab * 2 + ph;
        const unsigned short* A = Wqkv + (size_t)mt * 128 * NC;
        f32x4 acc[4][4] = {};
        for (int kt = 0; kt < 4; ++kt) {
            __syncthreads();                   // lsA reads done; (1st) xTl visible
            stage_tile<128>(A, NC, kt * 64, lsA, t);
            __syncthreads();                   // stage landed (vmcnt drained)
            #pragma unroll
            for (int g = 0; g < 2; ++g) {
                const int ka = g * 64 + q * 16;           // A-buffer local kbyte
                const int kb = kt * 128 + ka;             // global kbyte in xTl
                bf16x8 af[4], bfr[4];
                #pragma unroll
                for (int m = 0; m < 4; ++m) af[m]  = frag_ld(lsA, wr + m * 16 + c15, ka);
                #pragma unroll
                for (int n = 0; n < 4; ++n) bfr[n] = fragB_ld(xTl, wc + n * 16 + c15, kb);
                if (slab == 1) {
                    #pragma unroll
                    for (int m = 0; m < 4; ++m)
                        #pragma unroll
                        for (int n = 0; n < 4; ++n)
                            acc[m][n] = __builtin_amdgcn_mfma_f32_16x16x32_bf16(
                                af[m], bfr[n], acc[m][n], 0, 0, 0);
                } else {
                    #pragma unroll
                    for (int m = 0; m < 4; ++m)
                        #pragma unroll
                        for (int n = 0; n < 4; ++n)
                            acc[m][n] = __builtin_amdgcn_mfma_f32_16x16x32_bf16(
                                bfr[n], af[m], acc[m][n], 0, 0, 0);
                }
            }
        }
        if (slab == 1) {
            // phiKT[n][c]: regs span c -> packed u16x4 along c
            unsigned short* dst = phiKT + (size_t)b * NN * NC;
            const int cb = ph * 128 + wr + q4;
            const int nb = nt * 128 + wc + c15;
            #pragma unroll
            for (int m = 0; m < 4; ++m)
                #pragma unroll
                for (int n = 0; n < 4; ++n) {
                    u16x4 pk;
                    #pragma unroll
                    for (int i = 0; i < 4; ++i) pk[i] = f2bf(phi_act(acc[m][n][i]));
                    *(u16x4*)(dst + (size_t)(nb + n * 16) * NC + cb + m * 16) = pk;
                }
        } else {
            // phi{Q,V}[c][n]: SWAP -> regs span n -> packed u16x4 along n
            unsigned short* dst = (slab == 0 ? phiQ : phiV) + (size_t)b * NC * NN;
            const int ob = ph * 128 + wr + c15;
            const int nb = nt * 128 + wc + q4;
            #pragma unroll
            for (int m = 0; m < 4; ++m)
                #pragma unroll
                for (int n = 0; n < 4; ++n) {
                    u16x4 pk;
                    #pragma unroll
                    for (int i = 0; i < 4; ++i) pk[i] = f2bf(phi_act(acc[m][n][i]));
                    *(u16x4*)(dst + (size_t)(ob + m * 16) * NN + nb + n * 16) = pk;
                }
        }
    }
}

// ------ K2: qvT_part[s][b][d][c] partials, split-K=8, XCD swizzle (r4) ------
__global__ __launch_bounds__(256) void k_qv(
    const unsigned short* __restrict__ phiQ, const unsigned short* __restrict__ phiV,
    float* __restrict__ qvTp)
{
    __shared__ char lds[32768];
    const int bid = (blockIdx.x & 7) * 64 + (blockIdx.x >> 3);   // 512 = 8*64
    const int s = bid & 7, nt = (bid >> 3) & 1, mt = (bid >> 4) & 1, b = bid >> 5;
    const unsigned short* A  = phiQ + ((size_t)b * NC + mt * 128) * NN;
    const unsigned short* BT = phiV + ((size_t)b * NC + nt * 128) * NN;
    f32x4 acc[4][4] = {};
    gemm128<false>(A, NN, BT, NN, s * 512, 8, lds, lds + 16384, acc);

    const int lane = threadIdx.x & 63, w = threadIdx.x >> 6;
    const int wr = (w >> 1) * 64, wc = (w & 1) * 64;
    const int q4 = (lane >> 4) * 4, c15 = lane & 15;
    float* dst = qvTp + (((size_t)s * NB + b) << 16);
    const int c0 = mt * 128 + wr + q4;
    const int d0 = nt * 128 + wc + c15;
    #pragma unroll
    for (int m = 0; m < 4; ++m)
        #pragma unroll
        for (int n = 0; n < 4; ++n)
            *(f32x4*)(dst + (size_t)(d0 + n * 16) * NC + c0 + m * 16) = acc[m][n];
}

// ------ K2b: qvT[b][d][c] bf16 = sum_s partials -----------------------------
__global__ __launch_bounds__(256) void k_qvred(
    const float* __restrict__ p, unsigned short* __restrict__ qvT)
{
    const size_t i = (size_t)blockIdx.x * 256 + threadIdx.x;  // 262144 f32x4 units
    const f32x4* pv = (const f32x4*)p;
    f32x4 v = pv[i];
    #pragma unroll
    for (int s = 1; s < 8; ++s) v = v + pv[i + (size_t)s * 262144];
    u16x4 o;
    #pragma unroll
    for (int j = 0; j < 4; ++j) o[j] = f2bf(v[j]);
    ((u16x4*)qvT)[i] = o;
}

// ------ K3: Mb[b][o][d] = Wo @ qv  (SWAP: regs span d) -----------------------
__global__ __launch_bounds__(256) void k_mproj(
    const unsigned short* __restrict__ Wob, const unsigned short* __restrict__ qvT,
    unsigned short* __restrict__ Mb)
{
    __shared__ char lds[32768];
    const int bid = blockIdx.x;                    // 64 blocks
    const int nt = bid & 1, mt = (bid >> 1) & 1, b = bid >> 2;
    const unsigned short* A  = Wob + mt * 128 * NC;
    const unsigned short* BT = qvT + ((size_t)b << 16) + nt * 128 * NC;
    f32x4 acc[4][4] = {};
    gemm128<true>(A, NC, BT, NC, 0, 4, lds, lds + 16384, acc);

    const int lane = threadIdx.x & 63, w = threadIdx.x >> 6;
    const int wr = (w >> 1) * 64, wc = (w & 1) * 64;
    const int q4 = (lane >> 4) * 4, c15 = lane & 15;
    unsigned short* dst = Mb + ((size_t)b << 16);
    const int ob = mt * 128 + wr + c15;
    const int db = nt * 128 + wc + q4;
    #pragma unroll
    for (int m = 0; m < 4; ++m)
        #pragma unroll
        for (int n = 0; n < 4; ++n) {
            u16x4 pk;
            #pragma unroll
            for (int i = 0; i < 4; ++i) pk[i] = f2bf(acc[m][n][i]);
            *(u16x4*)(dst + (size_t)(ob + m * 16) * NC + db + n * 16) = pk;
        }
}

// ------ K4: out[b][o][n] = Mb @ phiK + bo  (r2 form, 1024 blocks) -----------
__global__ __launch_bounds__(256) void k_out(
    const unsigned short* __restrict__ Mb, const unsigned short* __restrict__ phiKT,
    const float* __restrict__ bo, float* __restrict__ out)
{
    __shared__ char lds[32768];
    const int bid = blockIdx.x;                    // 1024 blocks
    const int nt = bid & 31, mt = (bid >> 5) & 1, b = bid >> 6;
    const unsigned short* A  = Mb + ((size_t)b << 16) + mt * 128 * NC;
    const unsigned short* BT = phiKT + (size_t)b * NN * NC + (size_t)nt * 128 * NC;
    f32x4 acc[4][4] = {};
    gemm128<true>(A, NC, BT, NC, 0, 4, lds, lds + 16384, acc);

    const int lane = threadIdx.x & 63, w = threadIdx.x >> 6;
    const int wr = (w >> 1) * 64, wc = (w & 1) * 64;
    const int q4 = (lane >> 4) * 4, c15 = lane & 15;
    float* dst = out + (size_t)b * NC * NN;
    #pragma unroll
    for (int m = 0; m < 4; ++m) {
        const int o  = mt * 128 + wr + m * 16 + c15;
        const float bb = bo[o];
        #pragma unroll
        for (int n = 0; n < 4; ++n) {
            f32x4 v = acc[m][n];
            #pragma unroll
            for (int i = 0; i < 4; ++i) v[i] += bb;
            *(f32x4*)(dst + (size_t)o * NN + nt * 128 + wc + n * 16 + q4) = v;
        }
    }
}

// ---------------------------------------------------------------------------
extern "C" void kernel_launch(void* const* d_in, const int* in_sizes, int n_in,
                              void* d_out, int out_size, void* d_ws, size_t ws_size,
                              hipStream_t stream)
{
    (void)in_sizes; (void)n_in; (void)out_size; (void)ws_size;
    const float* x  = (const float*)d_in[0];
    const float* Wq = (const float*)d_in[1];
    const float* Wk = (const float*)d_in[2];
    const float* Wv = (const float*)d_in[3];
    const float* Wo = (const float*)d_in[4];
    const float* bo = (const float*)d_in[5];
    float* out = (float*)d_out;

    char* ws = (char*)d_ws;
    size_t off = 0;
    auto alloc = [&](size_t bytes) {
        void* p = ws + off;
        off += (bytes + 255) & ~(size_t)255;
        return p;
    };
    unsigned short* phiQ  = (unsigned short*)alloc((size_t)NB * NC * NN * 2); // 32 MiB
    unsigned short* phiV  = (unsigned short*)alloc((size_t)NB * NC * NN * 2); // 32 MiB
    unsigned short* phiKT = (unsigned short*)alloc((size_t)NB * NN * NC * 2); // 32 MiB
    float*          qvTp  = (float*)alloc((size_t)8 * NB * NC * NC * 4);      // 32 MiB
    unsigned short* qvT   = (unsigned short*)alloc((size_t)NB * NC * NC * 2); //  2 MiB
    unsigned short* Mb    = (unsigned short*)alloc((size_t)NB * NC * NC * 2); //  2 MiB
    unsigned short* Wqkv  = (unsigned short*)alloc((size_t)768 * NC * 2);
    unsigned short* Wob   = (unsigned short*)alloc((size_t)NC * NC * 2);

    k_wcvt<<<1024, 256, 0, stream>>>(Wq, Wk, Wv, Wo, Wqkv, Wob);
    k_projm<<<1024, 256, 0, stream>>>(Wqkv, x, phiQ, phiKT, phiV);
    k_qv<<<512, 256, 0, stream>>>(phiQ, phiV, qvTp);
    k_qvred<<<1024, 256, 0, stream>>>(qvTp, qvT);
    k_mproj<<<64, 256, 0, stream>>>(Wob, qvT, Mb);
    k_out<<<1024, 256, 0, stream>>>(Mb, phiKT, bo, out);
}

// Round 12
// 121.931 us; speedup vs baseline: 1.2037x; 1.0078x over previous
//
#include <hip/hip_runtime.h>
#include <hip/hip_bf16.h>

// ConvolutionalAttention2D: B=16, C=256, N=H*W=4096.
// out = (Wo * (phiQ @ phiV^T)) @ phiK + bo, phiX = elu(Wx @ x)+1
// bf16 MFMA (16x16x32), fp32 accumulate.
// Round 12: best-of-all-rounds consolidation — fused k_pre + r2 k_proj
// (65us combined), XCD-swizzled k_qv (r4/r11-proven), r2 k_out. No other
// structure: counted-vmcnt / fat-tile / in-block-transpose all regressed.

typedef short  bf16x8 __attribute__((ext_vector_type(8)));
typedef float  f32x4  __attribute__((ext_vector_type(4)));
typedef unsigned short u16x4 __attribute__((ext_vector_type(4)));

#define NB 16
#define NC 256
#define NN 4096

__device__ __forceinline__ unsigned short f2bf(float f) {
    union { float f; unsigned u; } v; v.f = f;
    unsigned r = v.u + 0x7FFFu + ((v.u >> 16) & 1u);
    return (unsigned short)(r >> 16);
}

__device__ __forceinline__ float phi_act(float v) {
    return v > 0.f ? v + 1.f : __expf(v);
}

__device__ __forceinline__ void gload_lds16(const void* g, void* l) {
    __builtin_amdgcn_global_load_lds(
        (const __attribute__((address_space(1))) void*)g,
        (__attribute__((address_space(3))) void*)l, 16, 0, 0);
}

// Stage a 128row x 64k bf16 tile (16 KB) into linear LDS with XOR-swizzled
// SOURCE address (both-sides swizzle; reads use frag_ld's matching XOR).
__device__ __forceinline__ void stage_tile(
    const unsigned short* __restrict__ src, int ld, int kb, char* lds, int t)
{
    const int kslot  = t & 7;
    const int rbase  = t >> 3;                         // 0..31
    const int srcOff = (kslot * 16) ^ ((rbase & 7) << 4);
    const int wbase  = (t >> 6) * 1024;                // wave-uniform
    #pragma unroll
    for (int i = 0; i < 4; ++i) {
        const int r = i * 32 + rbase;
        const char* g = (const char*)(src + (size_t)r * ld + kb) + srcOff;
        gload_lds16(g, lds + i * 4096 + wbase);
    }
}

// Swizzled fragment read: row-major [128][64] bf16, byte ^= ((row&7)<<4)
__device__ __forceinline__ bf16x8 frag_ld(const char* lds, int row, int kbyte) {
    return *(const bf16x8*)(lds + row * 128 + (kbyte ^ ((row & 7) << 4)));
}

// ---------------------------------------------------------------------------
// r2 2-barrier 128x128 engine — known good.
// SWAP=false: acc[m][n] rows = A-dim (wr+m*16+q4+i), cols = B-dim (wc+n*16+c15)
// SWAP=true : acc[m][n] rows = B-dim (wc+n*16+q4+i), cols = A-dim (wr+m*16+c15)
// ---------------------------------------------------------------------------
template<bool SWAP>
__device__ __forceinline__ void gemm128(
    const unsigned short* __restrict__ A, int lda,
    const unsigned short* __restrict__ BT, int ldb,
    int k0, int nk, char* lsA, char* lsB, f32x4 (&acc)[4][4])
{
    const int t = threadIdx.x;
    const int lane = t & 63;
    const int w  = t >> 6;
    const int wr = (w >> 1) * 64, wc = (w & 1) * 64;
    const int q  = lane >> 4, c15 = lane & 15;

    for (int kt = 0; kt < nk; ++kt) {
        const int kb = k0 + kt * 64;
        if (kt) __syncthreads();            // prior reads done before overwrite
        stage_tile(A,  lda, kb, lsA, t);
        stage_tile(BT, ldb, kb, lsB, t);
        __syncthreads();                    // compiler drains vmcnt before barrier
        #pragma unroll
        for (int g = 0; g < 2; ++g) {
            const int kbyte = g * 64 + q * 16;
            bf16x8 af[4], bfr[4];
            #pragma unroll
            for (int m = 0; m < 4; ++m) af[m]  = frag_ld(lsA, wr + m * 16 + c15, kbyte);
            #pragma unroll
            for (int n = 0; n < 4; ++n) bfr[n] = frag_ld(lsB, wc + n * 16 + c15, kbyte);
            #pragma unroll
            for (int m = 0; m < 4; ++m)
                #pragma unroll
                for (int n = 0; n < 4; ++n)
                    acc[m][n] = SWAP
                        ? __builtin_amdgcn_mfma_f32_16x16x32_bf16(bfr[n], af[m], acc[m][n], 0, 0, 0)
                        : __builtin_amdgcn_mfma_f32_16x16x32_bf16(af[m], bfr[n], acc[m][n], 0, 0, 0);
        }
    }
}

// ---- K0 (fused): xpose (blocks 0..4095) + weight convert (blocks 4096..5119)
__global__ __launch_bounds__(256) void k_pre(
    const float* __restrict__ x,
    const float* __restrict__ Wq, const float* __restrict__ Wk,
    const float* __restrict__ Wv, const float* __restrict__ Wo,
    unsigned short* __restrict__ xT,
    unsigned short* __restrict__ Wqkv, unsigned short* __restrict__ Wob)
{
    __shared__ float tile[64][68];
    const int id = blockIdx.x;
    if (id >= 4096) {
        int i = (id - 4096) * 256 + threadIdx.x;   // 262144 total
        if      (i < 65536)  Wqkv[i] = f2bf(Wq[i]);
        else if (i < 131072) Wqkv[i] = f2bf(Wk[i - 65536]);
        else if (i < 196608) Wqkv[i] = f2bf(Wv[i - 131072]);
        else                 Wob[i - 196608] = f2bf(Wo[i - 196608]);
        return;
    }
    const int b  = id >> 8;
    const int n0 = (id & 63) * 64, c0 = ((id >> 6) & 3) * 64;
    const int t  = threadIdx.x;
    const float* xp = x + ((size_t)b * NC + c0) * NN + n0;
    const int cc = t >> 4, nq = t & 15;
    #pragma unroll
    for (int j = 0; j < 4; ++j) {
        const int c = j * 16 + cc;
        f32x4 v = *(const f32x4*)(xp + (size_t)c * NN + nq * 4);
        *(f32x4*)&tile[c][nq * 4] = v;
    }
    __syncthreads();
    unsigned short* op = xT + ((size_t)b * NN + n0) * NC + c0;
    const int nn0 = t >> 4, cq = t & 15;
    #pragma unroll
    for (int j = 0; j < 4; ++j) {
        const int nn = j * 16 + nn0;
        u16x4 o;
        #pragma unroll
        for (int ii = 0; ii < 4; ++ii) o[ii] = f2bf(tile[cq * 4 + ii][nn]);
        *(u16x4*)(op + (size_t)nn * NC + cq * 4) = o;
    }
}

// ------ K1: [phiQ;phiK^T;phiV] = phi(Wqkv @ x); grid 16b*6mt*32nt (r2) ------
__global__ __launch_bounds__(256) void k_proj(
    const unsigned short* __restrict__ Wqkv, const unsigned short* __restrict__ xT,
    unsigned short* __restrict__ phiQ, unsigned short* __restrict__ phiKT,
    unsigned short* __restrict__ phiV)
{
    __shared__ char lds[32768];
    const int bid = blockIdx.x;                    // 3072
    const int nt  = bid & 31;
    const int mt  = (bid >> 5) % 6;
    const int b   = bid / 192;
    const unsigned short* A  = Wqkv + (size_t)mt * 128 * NC;
    const unsigned short* BT = xT + ((size_t)b * NN + nt * 128) * NC;

    const int lane = threadIdx.x & 63;
    const int w    = threadIdx.x >> 6;
    const int wr   = (w >> 1) * 64, wc = (w & 1) * 64;
    const int q4   = (lane >> 4) * 4, c15 = lane & 15;
    const int p    = mt >> 1;                 // 0=Q, 1=K, 2=V

    f32x4 acc[4][4] = {};
    if (p == 1) {
        gemm128<false>(A, NC, BT, NC, 0, 4, lds, lds + 16384, acc);
        // phiKT[n][c]: regs span c -> packed u16x4 along c
        unsigned short* dst = phiKT + (size_t)b * NN * NC;
        const int cb = (mt & 1) * 128 + wr + q4;
        const int nb = nt * 128 + wc + c15;
        #pragma unroll
        for (int m = 0; m < 4; ++m)
            #pragma unroll
            for (int n = 0; n < 4; ++n) {
                u16x4 pk;
                #pragma unroll
                for (int i = 0; i < 4; ++i) pk[i] = f2bf(phi_act(acc[m][n][i]));
                *(u16x4*)(dst + (size_t)(nb + n * 16) * NC + cb + m * 16) = pk;
            }
    } else {
        gemm128<true>(A, NC, BT, NC, 0, 4, lds, lds + 16384, acc);
        // phi{Q,V}[c][n]: SWAP -> regs span n -> packed u16x4 along n
        unsigned short* dst = (p == 0 ? phiQ : phiV) + (size_t)b * NC * NN;
        const int ob = (mt & 1) * 128 + wr + c15;
        const int nb = nt * 128 + wc + q4;
        #pragma unroll
        for (int m = 0; m < 4; ++m)
            #pragma unroll
            for (int n = 0; n < 4; ++n) {
                u16x4 pk;
                #pragma unroll
                for (int i = 0; i < 4; ++i) pk[i] = f2bf(phi_act(acc[m][n][i]));
                *(u16x4*)(dst + (size_t)(ob + m * 16) * NN + nb + n * 16) = pk;
            }
    }
}

// ------ K2: qvT_part[s][b][d][c] partials, split-K=8, XCD chunk swizzle -----
__global__ __launch_bounds__(256) void k_qv(
    const unsigned short* __restrict__ phiQ, const unsigned short* __restrict__ phiV,
    float* __restrict__ qvTp)
{
    __shared__ char lds[32768];
    const int bid = (blockIdx.x & 7) * 64 + (blockIdx.x >> 3);   // 512 = 8*64
    const int s = bid & 7, nt = (bid >> 3) & 1, mt = (bid >> 4) & 1, b = bid >> 5;
    const unsigned short* A  = phiQ + ((size_t)b * NC + mt * 128) * NN;
    const unsigned short* BT = phiV + ((size_t)b * NC + nt * 128) * NN;
    f32x4 acc[4][4] = {};
    gemm128<false>(A, NN, BT, NN, s * 512, 8, lds, lds + 16384, acc);

    const int lane = threadIdx.x & 63, w = threadIdx.x >> 6;
    const int wr = (w >> 1) * 64, wc = (w & 1) * 64;
    const int q4 = (lane >> 4) * 4, c15 = lane & 15;
    float* dst = qvTp + (((size_t)s * NB + b) << 16);
    const int c0 = mt * 128 + wr + q4;
    const int d0 = nt * 128 + wc + c15;
    #pragma unroll
    for (int m = 0; m < 4; ++m)
        #pragma unroll
        for (int n = 0; n < 4; ++n)
            *(f32x4*)(dst + (size_t)(d0 + n * 16) * NC + c0 + m * 16) = acc[m][n];
}

// ------ K2b: qvT[b][d][c] bf16 = sum_s partials -----------------------------
__global__ __launch_bounds__(256) void k_qvred(
    const float* __restrict__ p, unsigned short* __restrict__ qvT)
{
    const size_t i = (size_t)blockIdx.x * 256 + threadIdx.x;  // 262144 f32x4 units
    const f32x4* pv = (const f32x4*)p;
    f32x4 v = pv[i];
    #pragma unroll
    for (int s = 1; s < 8; ++s) v = v + pv[i + (size_t)s * 262144];
    u16x4 o;
    #pragma unroll
    for (int j = 0; j < 4; ++j) o[j] = f2bf(v[j]);
    ((u16x4*)qvT)[i] = o;
}

// ------ K3: Mb[b][o][d] = Wo @ qv  (SWAP: regs span d) -----------------------
__global__ __launch_bounds__(256) void k_mproj(
    const unsigned short* __restrict__ Wob, const unsigned short* __restrict__ qvT,
    unsigned short* __restrict__ Mb)
{
    __shared__ char lds[32768];
    const int bid = blockIdx.x;                    // 64 blocks
    const int nt = bid & 1, mt = (bid >> 1) & 1, b = bid >> 2;
    const unsigned short* A  = Wob + mt * 128 * NC;
    const unsigned short* BT = qvT + ((size_t)b << 16) + nt * 128 * NC;
    f32x4 acc[4][4] = {};
    gemm128<true>(A, NC, BT, NC, 0, 4, lds, lds + 16384, acc);

    const int lane = threadIdx.x & 63, w = threadIdx.x >> 6;
    const int wr = (w >> 1) * 64, wc = (w & 1) * 64;
    const int q4 = (lane >> 4) * 4, c15 = lane & 15;
    unsigned short* dst = Mb + ((size_t)b << 16);
    const int ob = mt * 128 + wr + c15;
    const int db = nt * 128 + wc + q4;
    #pragma unroll
    for (int m = 0; m < 4; ++m)
        #pragma unroll
        for (int n = 0; n < 4; ++n) {
            u16x4 pk;
            #pragma unroll
            for (int i = 0; i < 4; ++i) pk[i] = f2bf(acc[m][n][i]);
            *(u16x4*)(dst + (size_t)(ob + m * 16) * NC + db + n * 16) = pk;
        }
}

// ------ K4: out[b][o][n] = Mb @ phiK + bo  (r2 form, 1024 blocks) -----------
__global__ __launch_bounds__(256) void k_out(
    const unsigned short* __restrict__ Mb, const unsigned short* __restrict__ phiKT,
    const float* __restrict__ bo, float* __restrict__ out)
{
    __shared__ char lds[32768];
    const int bid = blockIdx.x;                    // 1024 blocks
    const int nt = bid & 31, mt = (bid >> 5) & 1, b = bid >> 6;
    const unsigned short* A  = Mb + ((size_t)b << 16) + mt * 128 * NC;
    const unsigned short* BT = phiKT + (size_t)b * NN * NC + (size_t)nt * 128 * NC;
    f32x4 acc[4][4] = {};
    gemm128<true>(A, NC, BT, NC, 0, 4, lds, lds + 16384, acc);

    const int lane = threadIdx.x & 63, w = threadIdx.x >> 6;
    const int wr = (w >> 1) * 64, wc = (w & 1) * 64;
    const int q4 = (lane >> 4) * 4, c15 = lane & 15;
    float* dst = out + (size_t)b * NC * NN;
    #pragma unroll
    for (int m = 0; m < 4; ++m) {
        const int o  = mt * 128 + wr + m * 16 + c15;
        const float bb = bo[o];
        #pragma unroll
        for (int n = 0; n < 4; ++n) {
            f32x4 v = acc[m][n];
            #pragma unroll
            for (int i = 0; i < 4; ++i) v[i] += bb;
            *(f32x4*)(dst + (size_t)o * NN + nt * 128 + wc + n * 16 + q4) = v;
        }
    }
}

// ---------------------------------------------------------------------------
extern "C" void kernel_launch(void* const* d_in, const int* in_sizes, int n_in,
                              void* d_out, int out_size, void* d_ws, size_t ws_size,
                              hipStream_t stream)
{
    (void)in_sizes; (void)n_in; (void)out_size; (void)ws_size;
    const float* x  = (const float*)d_in[0];
    const float* Wq = (const float*)d_in[1];
    const float* Wk = (const float*)d_in[2];
    const float* Wv = (const float*)d_in[3];
    const float* Wo = (const float*)d_in[4];
    const float* bo = (const float*)d_in[5];
    float* out = (float*)d_out;

    char* ws = (char*)d_ws;
    size_t off = 0;
    auto alloc = [&](size_t bytes) {
        void* p = ws + off;
        off += (bytes + 255) & ~(size_t)255;
        return p;
    };
    unsigned short* xT    = (unsigned short*)alloc((size_t)NB * NN * NC * 2); // 32 MiB
    unsigned short* phiQ  = (unsigned short*)alloc((size_t)NB * NC * NN * 2); // 32 MiB
    unsigned short* phiV  = (unsigned short*)alloc((size_t)NB * NC * NN * 2); // 32 MiB
    unsigned short* phiKT = (unsigned short*)alloc((size_t)NB * NN * NC * 2); // 32 MiB
    unsigned short* qvT   = (unsigned short*)alloc((size_t)NB * NC * NC * 2); //  2 MiB
    unsigned short* Mb    = (unsigned short*)alloc((size_t)NB * NC * NC * 2); //  2 MiB
    unsigned short* Wqkv  = (unsigned short*)alloc((size_t)768 * NC * 2);
    unsigned short* Wob   = (unsigned short*)alloc((size_t)NC * NC * 2);
    float* qvTp = (float*)xT;   // alias: xT dead after k_proj; 8*16*64K*4B = 32 MiB

    k_pre<<<5120, 256, 0, stream>>>(x, Wq, Wk, Wv, Wo, xT, Wqkv, Wob);
    k_proj<<<3072, 256, 0, stream>>>(Wqkv, xT, phiQ, phiKT, phiV);
    k_qv<<<512, 256, 0, stream>>>(phiQ, phiV, qvTp);
    k_qvred<<<1024, 256, 0, stream>>>(qvTp, qvT);
    k_mproj<<<64, 256, 0, stream>>>(Wob, qvT, Mb);
    k_out<<<1024, 256, 0, stream>>>(Mb, phiKT, bo, out);
}

// Round 13
// 118.797 us; speedup vs baseline: 1.2355x; 1.0264x over previous
//
#include <hip/hip_runtime.h>
#include <hip/hip_bf16.h>

// ConvolutionalAttention2D: B=16, C=256, N=H*W=4096.
// out = (Wo * (phiQ @ phiV^T)) @ phiK + bo, phiX = elu(Wx @ x)+1
// bf16 MFMA (16x16x32), fp32 accumulate.
// Round 13: r12 config + two traffic cuts: (1) bf16 split-K partials for qv
// (halves qvTp round-trip), (2) XCD chunk swizzle on k_out (phiKT L2-resident).

typedef short  bf16x8 __attribute__((ext_vector_type(8)));
typedef float  f32x4  __attribute__((ext_vector_type(4)));
typedef unsigned short u16x4 __attribute__((ext_vector_type(4)));

#define NB 16
#define NC 256
#define NN 4096

__device__ __forceinline__ unsigned short f2bf(float f) {
    union { float f; unsigned u; } v; v.f = f;
    unsigned r = v.u + 0x7FFFu + ((v.u >> 16) & 1u);
    return (unsigned short)(r >> 16);
}

__device__ __forceinline__ float bf2f(unsigned short h) {
    union { unsigned u; float f; } v; v.u = (unsigned)h << 16;
    return v.f;
}

__device__ __forceinline__ float phi_act(float v) {
    return v > 0.f ? v + 1.f : __expf(v);
}

__device__ __forceinline__ void gload_lds16(const void* g, void* l) {
    __builtin_amdgcn_global_load_lds(
        (const __attribute__((address_space(1))) void*)g,
        (__attribute__((address_space(3))) void*)l, 16, 0, 0);
}

// Stage a 128row x 64k bf16 tile (16 KB) into linear LDS with XOR-swizzled
// SOURCE address (both-sides swizzle; reads use frag_ld's matching XOR).
__device__ __forceinline__ void stage_tile(
    const unsigned short* __restrict__ src, int ld, int kb, char* lds, int t)
{
    const int kslot  = t & 7;
    const int rbase  = t >> 3;                         // 0..31
    const int srcOff = (kslot * 16) ^ ((rbase & 7) << 4);
    const int wbase  = (t >> 6) * 1024;                // wave-uniform
    #pragma unroll
    for (int i = 0; i < 4; ++i) {
        const int r = i * 32 + rbase;
        const char* g = (const char*)(src + (size_t)r * ld + kb) + srcOff;
        gload_lds16(g, lds + i * 4096 + wbase);
    }
}

// Swizzled fragment read: row-major [128][64] bf16, byte ^= ((row&7)<<4)
__device__ __forceinline__ bf16x8 frag_ld(const char* lds, int row, int kbyte) {
    return *(const bf16x8*)(lds + row * 128 + (kbyte ^ ((row & 7) << 4)));
}

// ---------------------------------------------------------------------------
// r2 2-barrier 128x128 engine — known good.
// SWAP=false: acc[m][n] rows = A-dim (wr+m*16+q4+i), cols = B-dim (wc+n*16+c15)
// SWAP=true : acc[m][n] rows = B-dim (wc+n*16+q4+i), cols = A-dim (wr+m*16+c15)
// ---------------------------------------------------------------------------
template<bool SWAP>
__device__ __forceinline__ void gemm128(
    const unsigned short* __restrict__ A, int lda,
    const unsigned short* __restrict__ BT, int ldb,
    int k0, int nk, char* lsA, char* lsB, f32x4 (&acc)[4][4])
{
    const int t = threadIdx.x;
    const int lane = t & 63;
    const int w  = t >> 6;
    const int wr = (w >> 1) * 64, wc = (w & 1) * 64;
    const int q  = lane >> 4, c15 = lane & 15;

    for (int kt = 0; kt < nk; ++kt) {
        const int kb = k0 + kt * 64;
        if (kt) __syncthreads();            // prior reads done before overwrite
        stage_tile(A,  lda, kb, lsA, t);
        stage_tile(BT, ldb, kb, lsB, t);
        __syncthreads();                    // compiler drains vmcnt before barrier
        #pragma unroll
        for (int g = 0; g < 2; ++g) {
            const int kbyte = g * 64 + q * 16;
            bf16x8 af[4], bfr[4];
            #pragma unroll
            for (int m = 0; m < 4; ++m) af[m]  = frag_ld(lsA, wr + m * 16 + c15, kbyte);
            #pragma unroll
            for (int n = 0; n < 4; ++n) bfr[n] = frag_ld(lsB, wc + n * 16 + c15, kbyte);
            #pragma unroll
            for (int m = 0; m < 4; ++m)
                #pragma unroll
                for (int n = 0; n < 4; ++n)
                    acc[m][n] = SWAP
                        ? __builtin_amdgcn_mfma_f32_16x16x32_bf16(bfr[n], af[m], acc[m][n], 0, 0, 0)
                        : __builtin_amdgcn_mfma_f32_16x16x32_bf16(af[m], bfr[n], acc[m][n], 0, 0, 0);
        }
    }
}

// ---- K0 (fused): xpose (blocks 0..4095) + weight convert (blocks 4096..5119)
__global__ __launch_bounds__(256) void k_pre(
    const float* __restrict__ x,
    const float* __restrict__ Wq, const float* __restrict__ Wk,
    const float* __restrict__ Wv, const float* __restrict__ Wo,
    unsigned short* __restrict__ xT,
    unsigned short* __restrict__ Wqkv, unsigned short* __restrict__ Wob)
{
    __shared__ float tile[64][68];
    const int id = blockIdx.x;
    if (id >= 4096) {
        int i = (id - 4096) * 256 + threadIdx.x;   // 262144 total
        if      (i < 65536)  Wqkv[i] = f2bf(Wq[i]);
        else if (i < 131072) Wqkv[i] = f2bf(Wk[i - 65536]);
        else if (i < 196608) Wqkv[i] = f2bf(Wv[i - 131072]);
        else                 Wob[i - 196608] = f2bf(Wo[i - 196608]);
        return;
    }
    const int b  = id >> 8;
    const int n0 = (id & 63) * 64, c0 = ((id >> 6) & 3) * 64;
    const int t  = threadIdx.x;
    const float* xp = x + ((size_t)b * NC + c0) * NN + n0;
    const int cc = t >> 4, nq = t & 15;
    #pragma unroll
    for (int j = 0; j < 4; ++j) {
        const int c = j * 16 + cc;
        f32x4 v = *(const f32x4*)(xp + (size_t)c * NN + nq * 4);
        *(f32x4*)&tile[c][nq * 4] = v;
    }
    __syncthreads();
    unsigned short* op = xT + ((size_t)b * NN + n0) * NC + c0;
    const int nn0 = t >> 4, cq = t & 15;
    #pragma unroll
    for (int j = 0; j < 4; ++j) {
        const int nn = j * 16 + nn0;
        u16x4 o;
        #pragma unroll
        for (int ii = 0; ii < 4; ++ii) o[ii] = f2bf(tile[cq * 4 + ii][nn]);
        *(u16x4*)(op + (size_t)nn * NC + cq * 4) = o;
    }
}

// ------ K1: [phiQ;phiK^T;phiV] = phi(Wqkv @ x); grid 16b*6mt*32nt (r2) ------
__global__ __launch_bounds__(256) void k_proj(
    const unsigned short* __restrict__ Wqkv, const unsigned short* __restrict__ xT,
    unsigned short* __restrict__ phiQ, unsigned short* __restrict__ phiKT,
    unsigned short* __restrict__ phiV)
{
    __shared__ char lds[32768];
    const int bid = blockIdx.x;                    // 3072
    const int nt  = bid & 31;
    const int mt  = (bid >> 5) % 6;
    const int b   = bid / 192;
    const unsigned short* A  = Wqkv + (size_t)mt * 128 * NC;
    const unsigned short* BT = xT + ((size_t)b * NN + nt * 128) * NC;

    const int lane = threadIdx.x & 63;
    const int w    = threadIdx.x >> 6;
    const int wr   = (w >> 1) * 64, wc = (w & 1) * 64;
    const int q4   = (lane >> 4) * 4, c15 = lane & 15;
    const int p    = mt >> 1;                 // 0=Q, 1=K, 2=V

    f32x4 acc[4][4] = {};
    if (p == 1) {
        gemm128<false>(A, NC, BT, NC, 0, 4, lds, lds + 16384, acc);
        // phiKT[n][c]: regs span c -> packed u16x4 along c
        unsigned short* dst = phiKT + (size_t)b * NN * NC;
        const int cb = (mt & 1) * 128 + wr + q4;
        const int nb = nt * 128 + wc + c15;
        #pragma unroll
        for (int m = 0; m < 4; ++m)
            #pragma unroll
            for (int n = 0; n < 4; ++n) {
                u16x4 pk;
                #pragma unroll
                for (int i = 0; i < 4; ++i) pk[i] = f2bf(phi_act(acc[m][n][i]));
                *(u16x4*)(dst + (size_t)(nb + n * 16) * NC + cb + m * 16) = pk;
            }
    } else {
        gemm128<true>(A, NC, BT, NC, 0, 4, lds, lds + 16384, acc);
        // phi{Q,V}[c][n]: SWAP -> regs span n -> packed u16x4 along n
        unsigned short* dst = (p == 0 ? phiQ : phiV) + (size_t)b * NC * NN;
        const int ob = (mt & 1) * 128 + wr + c15;
        const int nb = nt * 128 + wc + q4;
        #pragma unroll
        for (int m = 0; m < 4; ++m)
            #pragma unroll
            for (int n = 0; n < 4; ++n) {
                u16x4 pk;
                #pragma unroll
                for (int i = 0; i < 4; ++i) pk[i] = f2bf(phi_act(acc[m][n][i]));
                *(u16x4*)(dst + (size_t)(ob + m * 16) * NN + nb + n * 16) = pk;
            }
    }
}

// ------ K2: qvT_part[s][b][d][c] bf16 partials, split-K=8, XCD swizzle ------
__global__ __launch_bounds__(256) void k_qv(
    const unsigned short* __restrict__ phiQ, const unsigned short* __restrict__ phiV,
    unsigned short* __restrict__ qvTp)
{
    __shared__ char lds[32768];
    const int bid = (blockIdx.x & 7) * 64 + (blockIdx.x >> 3);   // 512 = 8*64
    const int s = bid & 7, nt = (bid >> 3) & 1, mt = (bid >> 4) & 1, b = bid >> 5;
    const unsigned short* A  = phiQ + ((size_t)b * NC + mt * 128) * NN;
    const unsigned short* BT = phiV + ((size_t)b * NC + nt * 128) * NN;
    f32x4 acc[4][4] = {};
    gemm128<false>(A, NN, BT, NN, s * 512, 8, lds, lds + 16384, acc);

    const int lane = threadIdx.x & 63, w = threadIdx.x >> 6;
    const int wr = (w >> 1) * 64, wc = (w & 1) * 64;
    const int q4 = (lane >> 4) * 4, c15 = lane & 15;
    unsigned short* dst = qvTp + (((size_t)s * NB + b) << 16);
    const int c0 = mt * 128 + wr + q4;
    const int d0 = nt * 128 + wc + c15;
    #pragma unroll
    for (int m = 0; m < 4; ++m)
        #pragma unroll
        for (int n = 0; n < 4; ++n) {
            u16x4 pk;
            #pragma unroll
            for (int i = 0; i < 4; ++i) pk[i] = f2bf(acc[m][n][i]);
            *(u16x4*)(dst + (size_t)(d0 + n * 16) * NC + c0 + m * 16) = pk;
        }
}

// ------ K2b: qvT[b][d][c] bf16 = sum_s bf16 partials ------------------------
__global__ __launch_bounds__(256) void k_qvred(
    const unsigned short* __restrict__ p, unsigned short* __restrict__ qvT)
{
    const size_t i = (size_t)blockIdx.x * 256 + threadIdx.x;  // 262144 u16x4 units
    const u16x4* pv = (const u16x4*)p;
    f32x4 v = {0.f, 0.f, 0.f, 0.f};
    #pragma unroll
    for (int s = 0; s < 8; ++s) {
        u16x4 a = pv[i + (size_t)s * 262144];
        #pragma unroll
        for (int j = 0; j < 4; ++j) v[j] += bf2f(a[j]);
    }
    u16x4 o;
    #pragma unroll
    for (int j = 0; j < 4; ++j) o[j] = f2bf(v[j]);
    ((u16x4*)qvT)[i] = o;
}

// ------ K3: Mb[b][o][d] = Wo @ qv  (SWAP: regs span d) -----------------------
__global__ __launch_bounds__(256) void k_mproj(
    const unsigned short* __restrict__ Wob, const unsigned short* __restrict__ qvT,
    unsigned short* __restrict__ Mb)
{
    __shared__ char lds[32768];
    const int bid = blockIdx.x;                    // 64 blocks
    const int nt = bid & 1, mt = (bid >> 1) & 1, b = bid >> 2;
    const unsigned short* A  = Wob + mt * 128 * NC;
    const unsigned short* BT = qvT + ((size_t)b << 16) + nt * 128 * NC;
    f32x4 acc[4][4] = {};
    gemm128<true>(A, NC, BT, NC, 0, 4, lds, lds + 16384, acc);

    const int lane = threadIdx.x & 63, w = threadIdx.x >> 6;
    const int wr = (w >> 1) * 64, wc = (w & 1) * 64;
    const int q4 = (lane >> 4) * 4, c15 = lane & 15;
    unsigned short* dst = Mb + ((size_t)b << 16);
    const int ob = mt * 128 + wr + c15;
    const int db = nt * 128 + wc + q4;
    #pragma unroll
    for (int m = 0; m < 4; ++m)
        #pragma unroll
        for (int n = 0; n < 4; ++n) {
            u16x4 pk;
            #pragma unroll
            for (int i = 0; i < 4; ++i) pk[i] = f2bf(acc[m][n][i]);
            *(u16x4*)(dst + (size_t)(ob + m * 16) * NC + db + n * 16) = pk;
        }
}

// ------ K4: out[b][o][n] = Mb @ phiK + bo  (r2 form + XCD chunk swizzle) ----
__global__ __launch_bounds__(256) void k_out(
    const unsigned short* __restrict__ Mb, const unsigned short* __restrict__ phiKT,
    const float* __restrict__ bo, float* __restrict__ out)
{
    __shared__ char lds[32768];
    const int bid = (blockIdx.x & 7) * 128 + (blockIdx.x >> 3); // 1024 = 8*128
    const int nt = bid & 31, mt = (bid >> 5) & 1, b = bid >> 6;
    const unsigned short* A  = Mb + ((size_t)b << 16) + mt * 128 * NC;
    const unsigned short* BT = phiKT + (size_t)b * NN * NC + (size_t)nt * 128 * NC;
    f32x4 acc[4][4] = {};
    gemm128<true>(A, NC, BT, NC, 0, 4, lds, lds + 16384, acc);

    const int lane = threadIdx.x & 63, w = threadIdx.x >> 6;
    const int wr = (w >> 1) * 64, wc = (w & 1) * 64;
    const int q4 = (lane >> 4) * 4, c15 = lane & 15;
    float* dst = out + (size_t)b * NC * NN;
    #pragma unroll
    for (int m = 0; m < 4; ++m) {
        const int o  = mt * 128 + wr + m * 16 + c15;
        const float bb = bo[o];
        #pragma unroll
        for (int n = 0; n < 4; ++n) {
            f32x4 v = acc[m][n];
            #pragma unroll
            for (int i = 0; i < 4; ++i) v[i] += bb;
            *(f32x4*)(dst + (size_t)o * NN + nt * 128 + wc + n * 16 + q4) = v;
        }
    }
}

// ---------------------------------------------------------------------------
extern "C" void kernel_launch(void* const* d_in, const int* in_sizes, int n_in,
                              void* d_out, int out_size, void* d_ws, size_t ws_size,
                              hipStream_t stream)
{
    (void)in_sizes; (void)n_in; (void)out_size; (void)ws_size;
    const float* x  = (const float*)d_in[0];
    const float* Wq = (const float*)d_in[1];
    const float* Wk = (const float*)d_in[2];
    const float* Wv = (const float*)d_in[3];
    const float* Wo = (const float*)d_in[4];
    const float* bo = (const float*)d_in[5];
    float* out = (float*)d_out;

    char* ws = (char*)d_ws;
    size_t off = 0;
    auto alloc = [&](size_t bytes) {
        void* p = ws + off;
        off += (bytes + 255) & ~(size_t)255;
        return p;
    };
    unsigned short* xT    = (unsigned short*)alloc((size_t)NB * NN * NC * 2); // 32 MiB
    unsigned short* phiQ  = (unsigned short*)alloc((size_t)NB * NC * NN * 2); // 32 MiB
    unsigned short* phiV  = (unsigned short*)alloc((size_t)NB * NC * NN * 2); // 32 MiB
    unsigned short* phiKT = (unsigned short*)alloc((size_t)NB * NN * NC * 2); // 32 MiB
    unsigned short* qvT   = (unsigned short*)alloc((size_t)NB * NC * NC * 2); //  2 MiB
    unsigned short* Mb    = (unsigned short*)alloc((size_t)NB * NC * NC * 2); //  2 MiB
    unsigned short* Wqkv  = (unsigned short*)alloc((size_t)768 * NC * 2);
    unsigned short* Wob   = (unsigned short*)alloc((size_t)NC * NC * 2);
    unsigned short* qvTp = (unsigned short*)xT; // alias: xT dead after k_proj;
                                                // 8*16*64K*2B = 16 MiB

    k_pre<<<5120, 256, 0, stream>>>(x, Wq, Wk, Wv, Wo, xT, Wqkv, Wob);
    k_proj<<<3072, 256, 0, stream>>>(Wqkv, xT, phiQ, phiKT, phiV);
    k_qv<<<512, 256, 0, stream>>>(phiQ, phiV, qvTp);
    k_qvred<<<1024, 256, 0, stream>>>(qvTp, qvT);
    k_mproj<<<64, 256, 0, stream>>>(Wob, qvT, Mb);
    k_out<<<1024, 256, 0, stream>>>(Mb, phiKT, bo, out);
}